// Round 5
// baseline (219.645 us; speedup 1.0000x reference)
//
#include <hip/hip_runtime.h>
#include <stdint.h>

typedef unsigned short u16;
typedef __bf16 bfx8 __attribute__((ext_vector_type(8)));
typedef float f32x4 __attribute__((ext_vector_type(4)));

__device__ __forceinline__ u16 f2bf(float x) {
    unsigned int u = __float_as_uint(x);
    u += 0x7fffu + ((u >> 16) & 1u);
    return (u16)(u >> 16);
}
__device__ __forceinline__ float bf2f(u16 v) {
    return __uint_as_float(((unsigned)v) << 16);
}

__device__ __forceinline__ void async16(const void* g, void* l) {
    __builtin_amdgcn_global_load_lds(
        (const __attribute__((address_space(1))) unsigned int*)(uintptr_t)g,
        (__attribute__((address_space(3))) unsigned int*)(unsigned int)(uintptr_t)l,
        16, 0, 0);
}

#define S_BARRIER() asm volatile("s_barrier" ::: "memory")
#define WAIT_VM6() asm volatile("s_waitcnt vmcnt(6)" ::: "memory")
#define WAIT_VM5() asm volatile("s_waitcnt vmcnt(5)" ::: "memory")
#define WAIT_VM0() asm volatile("s_waitcnt vmcnt(0)" ::: "memory")
#define WAIT_LGKM0() asm volatile("s_waitcnt lgkmcnt(0)" ::: "memory")

// ---------------------------------------------------------------------------
// fused cast: 7 segments of f32 -> bf16, 8 elems/thread, one launch
// ---------------------------------------------------------------------------
struct CastArgs {
    const float* src[7];
    u16* dst[7];
    int nblk[7];
};
__global__ __launch_bounds__(256) void cast_all(CastArgs a) {
    int b = blockIdx.x, seg = 0;
    while (b >= a.nblk[seg]) { b -= a.nblk[seg]; ++seg; }
    int i = b * 256 + threadIdx.x;
    const float4* p = (const float4*)(a.src[seg] + (size_t)i * 8);
    float4 x = p[0], y = p[1];
    ushort4 o0, o1;
    o0.x = f2bf(x.x); o0.y = f2bf(x.y); o0.z = f2bf(x.z); o0.w = f2bf(x.w);
    o1.x = f2bf(y.x); o1.y = f2bf(y.y); o1.z = f2bf(y.z); o1.w = f2bf(y.w);
    ushort4* q = (ushort4*)(a.dst[seg] + (size_t)i * 8);
    q[0] = o0; q[1] = o1;
}

// ---------------------------------------------------------------------------
// RING GEMM (global_load_lds transport, round-2 proven): C = A[M,K]*Bw[N,K]^T
// BM=256, BN=BNv(128|64), BK=64, 8 waves (4M x 2N), wave tile 64 x BNv/2.
// 3-deep LDS ring, depth-2 prefetch, counted vmcnt.
// EPI 0 (BNv=128): QKV split epilogue (Q rows / K rows / V^T)
// EPI 2 (BNv=64):  outb = bf16(gelu(C + bias))
// ---------------------------------------------------------------------------
template <int EPI, int BNv>
__global__ __launch_bounds__(512, 2)
void gemm_ring(const u16* __restrict__ A, const u16* __restrict__ Bw,
               u16* __restrict__ outq, u16* __restrict__ outk,
               u16* __restrict__ vt, u16* __restrict__ outb,
               const float* __restrict__ bias, int M, int N, int K) {
    constexpr int NF = BNv / 32;           // B frags per wave (4 or 2)
    constexpr int BU = BNv / 64;           // B stage units per thread (2 or 1)
    constexpr int TS = 32768 + BNv * 128;  // ring tile stride bytes
    __shared__ __align__(1024) unsigned char lds[3 * TS];
    const int t = threadIdx.x;
    const int lane = t & 63, w = t >> 6;
    const int laneR = lane & 15, laneK = lane >> 4;
    const int wr = w >> 1, wc = w & 1;
    const int row0 = blockIdx.y * 256, col0 = blockIdx.x * BNv;
    const int nt = K >> 6;

    f32x4 acc[4][NF] = {};

    const u16* srcA[4];
    const u16* srcB[BU];
    unsigned dA[4], dB[BU];
#pragma unroll
    for (int i = 0; i < 4; ++i) {
        int li = i * 512 + t;
        int row = li >> 3, ko = li & 7;
        srcA[i] = A + (size_t)(row0 + row) * K + (ko ^ (row & 7)) * 8;
        dA[i] = li * 16;
    }
#pragma unroll
    for (int i = 0; i < BU; ++i) {
        int li = i * 512 + t;
        int row = li >> 3, ko = li & 7;
        srcB[i] = Bw + (size_t)(col0 + row) * K + (ko ^ (row & 7)) * 8;
        dB[i] = 32768 + li * 16;
    }

    auto stage = [&](int b, int tk, int h) {
        unsigned char* base = lds + b * TS;
        const int o = tk * 64;
        if (h == 0) {
            async16(srcA[0] + o, base + dA[0]);
            async16(srcA[1] + o, base + dA[1]);
            async16(srcB[0] + o, base + dB[0]);
        } else {
            async16(srcA[2] + o, base + dA[2]);
            async16(srcA[3] + o, base + dA[3]);
            if constexpr (BU == 2) async16(srcB[1] + o, base + dB[1]);
        }
    };

    stage(0, 0, 0); stage(0, 0, 1);
    stage(1, 1, 0); stage(1, 1, 1);

    for (int tk = 0; tk < nt; ++tk) {
        unsigned char* bufA = lds + (tk % 3) * TS;
        unsigned char* bufB = bufA + 32768;
        if (tk + 1 < nt) {
            if constexpr (BU == 2) { WAIT_VM6(); } else { WAIT_VM5(); }
        } else { WAIT_VM0(); }
        S_BARRIER();
        const bool pf = (tk + 2 < nt);
        const int nb = (tk + 2) % 3;
#pragma unroll
        for (int ks = 0; ks < 2; ++ks) {
            bfx8 af[4], bf[NF];
#pragma unroll
            for (int m = 0; m < 4; ++m) {
                int r = wr * 64 + m * 16 + laneR;
                int phys = (ks * 4 + laneK) ^ (r & 7);
                af[m] = *(const bfx8*)(bufA + r * 128 + phys * 16);
            }
#pragma unroll
            for (int n = 0; n < NF; ++n) {
                int r = wc * (BNv / 2) + n * 16 + laneR;
                int phys = (ks * 4 + laneK) ^ (r & 7);
                bf[n] = *(const bfx8*)(bufB + r * 128 + phys * 16);
            }
            if (pf) stage(nb, tk + 2, ks);
            S_BARRIER();
            __builtin_amdgcn_s_setprio(1);
#pragma unroll
            for (int m = 0; m < 4; ++m)
#pragma unroll
                for (int n = 0; n < NF; ++n)
                    acc[m][n] = __builtin_amdgcn_mfma_f32_16x16x32_bf16(
                        af[m], bf[n], acc[m][n], 0, 0, 0);
            __builtin_amdgcn_s_setprio(0);
            S_BARRIER();
        }
    }

#pragma unroll
    for (int m = 0; m < 4; ++m) {
        const int gr0 = row0 + wr * 64 + m * 16 + laneK * 4;
#pragma unroll
        for (int n = 0; n < NF; ++n) {
            const int gc = col0 + wc * (BNv / 2) + n * 16 + laneR;
            if constexpr (EPI == 0) {
                if (col0 < 1024) {
#pragma unroll
                    for (int r = 0; r < 4; ++r)
                        outq[(size_t)(gr0 + r) * 1024 + gc] = f2bf(acc[m][n][r]);
                } else if (col0 < 2048) {
#pragma unroll
                    for (int r = 0; r < 4; ++r)
                        outk[(size_t)(gr0 + r) * 1024 + (gc - 1024)] = f2bf(acc[m][n][r]);
                } else {
                    ushort4 o4;
                    o4.x = f2bf(acc[m][n][0]); o4.y = f2bf(acc[m][n][1]);
                    o4.z = f2bf(acc[m][n][2]); o4.w = f2bf(acc[m][n][3]);
                    *(ushort4*)(vt + (((size_t)(gr0 >> 12)) * 1024 + (gc - 2048)) * 4096 +
                                (gr0 & 4095)) = o4;
                }
            } else {  // EPI 2: gelu(C + bias) -> bf16
#pragma unroll
                for (int r = 0; r < 4; ++r) {
                    float xx = acc[m][n][r] + bias[gc];
                    outb[(size_t)(gr0 + r) * N + gc] =
                        f2bf(xx * 0.5f * (1.0f + erff(xx * 0.70710678118654752f)));
                }
            }
        }
    }
}

// ---------------------------------------------------------------------------
// REG-STAGED GEMM (A/B test vs global_load_lds): same geometry as ring BN=128.
// Transport: global_load_dwordx4 -> regs (issued 2 tiles ahead) ->
// ds_write_b128 into the non-active LDS buffer (1 tile ahead).
// Static set names (rule #20), 2 LDS buffers of 48KB.
// EPI 1: draftb = bf16(res + C)          (res f32)
// EPI 3: outf  = bf2f(draftb) + C + bias (f32 out)
// ---------------------------------------------------------------------------
template <int EPI>
__global__ __launch_bounds__(512, 2)
void gemm_rs(const u16* __restrict__ A, const u16* __restrict__ Bw,
             const float* __restrict__ res, u16* __restrict__ draftb,
             const float* __restrict__ bias, float* __restrict__ outf,
             int M, int N, int K) {
    __shared__ __align__(1024) unsigned char lds[98304];  // 2 x 49152
    const int t = threadIdx.x;
    const int lane = t & 63, w = t >> 6;
    const int laneR = lane & 15, laneK = lane >> 4;
    const int wr = w >> 1, wc = w & 1;
    const int row0 = blockIdx.y * 256, col0 = blockIdx.x * 128;
    const int nt = K >> 6;

    f32x4 acc[4][4] = {};

    const u16* srcA[4];
    const u16* srcB[2];
    unsigned dA[4], dB[2];
#pragma unroll
    for (int i = 0; i < 4; ++i) {
        int li = i * 512 + t;
        int row = li >> 3, ko = li & 7;
        srcA[i] = A + (size_t)(row0 + row) * K + ko * 8;           // logical source
        dA[i] = row * 128 + (ko ^ (row & 7)) * 16;                 // swizzled dest
    }
#pragma unroll
    for (int i = 0; i < 2; ++i) {
        int li = i * 512 + t;
        int row = li >> 3, ko = li & 7;
        srcB[i] = Bw + (size_t)(col0 + row) * K + ko * 8;
        dB[i] = 32768 + row * 128 + (ko ^ (row & 7)) * 16;
    }

    uint4 raA[4], rbA[2];   // set A
    uint4 raB[4], rbB[2];   // set B

#define RS_ISSUE(RA, RB, TK)                                                   \
    {                                                                          \
        const int o_ = (TK) * 64;                                              \
        _Pragma("unroll") for (int i = 0; i < 4; ++i)                          \
            RA[i] = *(const uint4*)(srcA[i] + o_);                             \
        _Pragma("unroll") for (int i = 0; i < 2; ++i)                          \
            RB[i] = *(const uint4*)(srcB[i] + o_);                             \
    }
#define RS_WRITE(RA, RB, BUF)                                                  \
    {                                                                          \
        unsigned char* base_ = lds + (BUF) * 49152;                            \
        _Pragma("unroll") for (int i = 0; i < 4; ++i)                          \
            *(uint4*)(base_ + dA[i]) = RA[i];                                  \
        _Pragma("unroll") for (int i = 0; i < 2; ++i)                          \
            *(uint4*)(base_ + dB[i]) = RB[i];                                  \
    }

    bfx8 af[4], bf[4];
    auto LDS_READS = [&](unsigned char* bufA, int ks) {
        unsigned char* bufB = bufA + 32768;
#pragma unroll
        for (int m = 0; m < 4; ++m) {
            int r = wr * 64 + m * 16 + laneR;
            int phys = (ks * 4 + laneK) ^ (r & 7);
            af[m] = *(const bfx8*)(bufA + r * 128 + phys * 16);
        }
#pragma unroll
        for (int n = 0; n < 4; ++n) {
            int r = wc * 64 + n * 16 + laneR;
            int phys = (ks * 4 + laneK) ^ (r & 7);
            bf[n] = *(const bfx8*)(bufB + r * 128 + phys * 16);
        }
    };
    auto DOMFMA = [&]() {
        __builtin_amdgcn_s_setprio(1);
#pragma unroll
        for (int m = 0; m < 4; ++m)
#pragma unroll
            for (int n = 0; n < 4; ++n)
                acc[m][n] = __builtin_amdgcn_mfma_f32_16x16x32_bf16(
                    af[m], bf[n], acc[m][n], 0, 0, 0);
        __builtin_amdgcn_s_setprio(0);
    };

    // prologue: setA <- tile0, setB <- tile1; write tile0 into buf0
    RS_ISSUE(raA, rbA, 0)
    RS_ISSUE(raB, rbB, (1 < nt ? 1 : 0))
    WAIT_VM6();           // setA landed (setB's 6 still in flight)
    RS_WRITE(raA, rbA, 0)
    WAIT_LGKM0();
    S_BARRIER();

    for (int tp = 0; tp < nt; tp += 2) {
        // ---- tile tp (reads buf0); setA free, setB holds L(tp+1) ----
        {
            unsigned char* bufA = lds + 0;
            LDS_READS(bufA, 0);
            const int ti = (tp + 2 < nt) ? tp + 2 : nt - 1;
            RS_ISSUE(raA, rbA, ti)              // setA <- L(tp+2)
            S_BARRIER();
            DOMFMA();
            S_BARRIER();
            LDS_READS(bufA, 1);
            if (tp + 1 < nt) {
                WAIT_VM6();                     // setB landed (setA in flight)
                RS_WRITE(raB, rbB, 1)           // buf1 <- tile tp+1
            }
            S_BARRIER();
            DOMFMA();
            WAIT_LGKM0();                       // ds_writes drained
            S_BARRIER();
        }
        if (tp + 1 >= nt) break;
        // ---- tile tp+1 (reads buf1); setB free, setA holds L(tp+2) ----
        {
            unsigned char* bufA = lds + 49152;
            LDS_READS(bufA, 0);
            const int ti = (tp + 3 < nt) ? tp + 3 : nt - 1;
            RS_ISSUE(raB, rbB, ti)              // setB <- L(tp+3)
            S_BARRIER();
            DOMFMA();
            S_BARRIER();
            LDS_READS(bufA, 1);
            if (tp + 2 < nt) {
                WAIT_VM6();                     // setA landed
                RS_WRITE(raA, rbA, 0)           // buf0 <- tile tp+2
            }
            S_BARRIER();
            DOMFMA();
            WAIT_LGKM0();
            S_BARRIER();
        }
    }

#pragma unroll
    for (int m = 0; m < 4; ++m) {
        const int gr0 = row0 + wr * 64 + m * 16 + laneK * 4;
#pragma unroll
        for (int n = 0; n < 4; ++n) {
            const int gc = col0 + wc * 64 + n * 16 + laneR;
#pragma unroll
            for (int r = 0; r < 4; ++r) {
                size_t idx = (size_t)(gr0 + r) * N + gc;
                if constexpr (EPI == 1) {
                    draftb[idx] = f2bf(res[idx] + acc[m][n][r]);
                } else {
                    outf[idx] = bf2f(draftb[idx]) + acc[m][n][r] + bias[gc];
                }
            }
        }
    }
#undef RS_ISSUE
#undef RS_WRITE
}

// ---------------------------------------------------------------------------
// banded attention: WINDOW=32, 32-query tiles, 64-key band [i0-32, i0+31]
// ---------------------------------------------------------------------------
__global__ __launch_bounds__(256, 2)
void attn_kernel(const u16* __restrict__ Q, const u16* __restrict__ K,
                 const u16* __restrict__ vt, u16* __restrict__ O) {
    constexpr int H = 1024, S = 4096;
    const int t = threadIdx.x, lane = t & 63, w = t >> 6;
    const int laneR = lane & 15, laneK = lane >> 4;
    const int tile = blockIdx.x;
    const int batch = tile >> 7;
    const int i0 = (tile & 127) * 32;
    const size_t base = (size_t)batch * S * H;

    __shared__ __align__(16) float S4[4][32][64];
    __shared__ __align__(16) u16 P[32][72];

    f32x4 sc[2][4] = {};
    for (int h = w * 256; h < w * 256 + 256; h += 32) {
        bfx8 qa[2];
#pragma unroll
        for (int m = 0; m < 2; ++m) {
            size_t row = (size_t)(i0 + m * 16 + laneR);
            qa[m] = *(const bfx8*)(Q + base + row * H + h + laneK * 8);
        }
        bfx8 kb[4];
#pragma unroll
        for (int n = 0; n < 4; ++n) {
            int j = i0 - 32 + n * 16 + laneR;
            int jc = j < 0 ? 0 : j;
            kb[n] = *(const bfx8*)(K + base + (size_t)jc * H + h + laneK * 8);
        }
#pragma unroll
        for (int m = 0; m < 2; ++m)
#pragma unroll
            for (int n = 0; n < 4; ++n)
                sc[m][n] = __builtin_amdgcn_mfma_f32_16x16x32_bf16(
                    qa[m], kb[n], sc[m][n], 0, 0, 0);
    }
#pragma unroll
    for (int m = 0; m < 2; ++m)
#pragma unroll
        for (int n = 0; n < 4; ++n)
#pragma unroll
            for (int r = 0; r < 4; ++r)
                S4[w][m * 16 + laneK * 4 + r][n * 16 + laneR] = sc[m][n][r];
    __syncthreads();

    {
        int q = t >> 3;
        int c0 = (t & 7) * 8;
        int lo = q + 1;
        if (32 - i0 > lo) lo = 32 - i0;
        int hi = q + 32;
        float vals[8];
        float mx = -1e30f;
#pragma unroll
        for (int c = 0; c < 8; ++c) {
            int cc = c0 + c;
            float v = (S4[0][q][cc] + S4[1][q][cc] + S4[2][q][cc] + S4[3][q][cc]) * 0.03125f;
            bool valid = (cc >= lo) && (cc <= hi);
            vals[c] = valid ? v : -1e30f;
            if (vals[c] > mx) mx = vals[c];
        }
#pragma unroll
        for (int d = 1; d < 8; d <<= 1) {
            float o = __shfl_xor(mx, d);
            if (o > mx) mx = o;
        }
        float sum = 0.f;
        float es[8];
#pragma unroll
        for (int c = 0; c < 8; ++c) {
            es[c] = (vals[c] > -1e29f) ? __expf(vals[c] - mx) : 0.f;
            sum += es[c];
        }
#pragma unroll
        for (int d = 1; d < 8; d <<= 1) sum += __shfl_xor(sum, d);
        float inv = 1.0f / sum;
#pragma unroll
        for (int c = 0; c < 8; ++c) P[q][c0 + c] = f2bf(es[c] * inv);
    }
    __syncthreads();

    for (int nc = 0; nc < 4; ++nc) {
        int ncol = w * 256 + nc * 64;
        f32x4 o[2][4] = {};
#pragma unroll
        for (int ks = 0; ks < 2; ++ks) {
            bfx8 pa[2];
#pragma unroll
            for (int m = 0; m < 2; ++m)
                pa[m] = *(const bfx8*)(&P[m * 16 + laneR][ks * 32 + laneK * 8]);
            int t0 = i0 - 32 + ks * 32 + laneK * 8;
            if (t0 < 0) t0 = 0;
#pragma unroll
            for (int n = 0; n < 4; ++n) {
                int c = ncol + n * 16 + laneR;
                bfx8 vb = *(const bfx8*)(vt + ((size_t)batch * 1024 + c) * 4096 + t0);
#pragma unroll
                for (int m = 0; m < 2; ++m)
                    o[m][n] = __builtin_amdgcn_mfma_f32_16x16x32_bf16(
                        pa[m], vb, o[m][n], 0, 0, 0);
            }
        }
#pragma unroll
        for (int m = 0; m < 2; ++m)
#pragma unroll
            for (int n = 0; n < 4; ++n)
#pragma unroll
                for (int r = 0; r < 4; ++r) {
                    size_t row = (size_t)(i0 + m * 16 + laneK * 4 + r);
                    O[base + row * H + ncol + n * 16 + laneR] = f2bf(o[m][n][r]);
                }
    }
}

// ---------------------------------------------------------------------------
// LayerNorm over H=1024, one block per row, bf16 in -> bf16 out
// ---------------------------------------------------------------------------
__global__ __launch_bounds__(256)
void ln_kernel(const u16* __restrict__ xb, const float* __restrict__ gw,
               const float* __restrict__ gb, u16* __restrict__ out) {
    const int row = blockIdx.x, t = threadIdx.x;
    const ushort4 dv = ((const ushort4*)(xb + (size_t)row * 1024))[t];
    float4 v;
    v.x = bf2f(dv.x); v.y = bf2f(dv.y); v.z = bf2f(dv.z); v.w = bf2f(dv.w);
    float s = v.x + v.y + v.z + v.w;
    float s2 = v.x * v.x + v.y * v.y + v.z * v.z + v.w * v.w;
#pragma unroll
    for (int d = 1; d < 64; d <<= 1) {
        s += __shfl_xor(s, d);
        s2 += __shfl_xor(s2, d);
    }
    __shared__ float red[8];
    int lane = t & 63, wv = t >> 6;
    if (lane == 0) { red[wv] = s; red[4 + wv] = s2; }
    __syncthreads();
    float S1 = red[0] + red[1] + red[2] + red[3];
    float S2 = red[4] + red[5] + red[6] + red[7];
    float mu = S1 * (1.0f / 1024.0f);
    float var = S2 * (1.0f / 1024.0f) - mu * mu;
    float rstd = rsqrtf(var + 1e-5f);
    const float4 wv4 = ((const float4*)gw)[t];
    const float4 bv4 = ((const float4*)gb)[t];
    ushort4 o;
    o.x = f2bf((v.x - mu) * rstd * wv4.x + bv4.x);
    o.y = f2bf((v.y - mu) * rstd * wv4.y + bv4.y);
    o.z = f2bf((v.z - mu) * rstd * wv4.z + bv4.z);
    o.w = f2bf((v.w - mu) * rstd * wv4.w + bv4.w);
    ((ushort4*)(out + (size_t)row * 1024))[t] = o;
}

// ---------------------------------------------------------------------------
extern "C" void kernel_launch(void* const* d_in, const int* in_sizes, int n_in,
                              void* d_out, int out_size, void* d_ws, size_t ws_size,
                              hipStream_t stream) {
    const float* x   = (const float*)d_in[0];
    const float* Wq  = (const float*)d_in[1];
    const float* Wk  = (const float*)d_in[2];
    const float* Wv  = (const float*)d_in[3];
    const float* Wo  = (const float*)d_in[4];
    const float* lnw = (const float*)d_in[5];
    const float* lnb = (const float*)d_in[6];
    const float* W1  = (const float*)d_in[7];
    const float* b1  = (const float*)d_in[8];
    const float* W2  = (const float*)d_in[9];
    const float* b2  = (const float*)d_in[10];
    (void)in_sizes; (void)n_in; (void)out_size; (void)ws_size;

    const int M = 8192, H = 1024, Hh = 512;

    char* ws = (char*)d_ws;
    size_t off = 0;
    auto alloc = [&](size_t bytes) {
        char* p = ws + off;
        off += (bytes + 255) & ~(size_t)255;
        return p;
    };
    u16* Xb     = (u16*)alloc((size_t)M * H * 2);      // reused as Attb
    u16* Wqkvb  = (u16*)alloc((size_t)3 * H * H * 2);
    u16* Wob    = (u16*)alloc((size_t)H * H * 2);
    u16* W1b    = (u16*)alloc((size_t)Hh * H * 2);
    u16* W2b    = (u16*)alloc((size_t)H * Hh * 2);
    u16* Qb     = (u16*)alloc((size_t)M * H * 2);      // reused as hlnb
    u16* Kb     = (u16*)alloc((size_t)M * H * 2);      // reused as Gb
    u16* Vt     = (u16*)alloc((size_t)M * H * 2);
    u16* draftb = (u16*)alloc((size_t)M * H * 2);      // bf16 draft
    u16* Attb = Xb;
    u16* hlnb = Qb;
    u16* Gb   = Kb;
    float* outp = (float*)d_out;

    CastArgs ca;
    ca.src[0] = x;  ca.dst[0] = Xb;                        ca.nblk[0] = (M * H / 8) / 256;
    ca.src[1] = Wq; ca.dst[1] = Wqkvb;                     ca.nblk[1] = (H * H / 8) / 256;
    ca.src[2] = Wk; ca.dst[2] = Wqkvb + (size_t)H * H;     ca.nblk[2] = (H * H / 8) / 256;
    ca.src[3] = Wv; ca.dst[3] = Wqkvb + (size_t)2 * H * H; ca.nblk[3] = (H * H / 8) / 256;
    ca.src[4] = Wo; ca.dst[4] = Wob;                       ca.nblk[4] = (H * H / 8) / 256;
    ca.src[5] = W1; ca.dst[5] = W1b;                       ca.nblk[5] = (Hh * H / 8) / 256;
    ca.src[6] = W2; ca.dst[6] = W2b;                       ca.nblk[6] = (H * Hh / 8) / 256;
    int totblk = 0;
    for (int i = 0; i < 7; ++i) totblk += ca.nblk[i];
    cast_all<<<dim3(totblk), dim3(256), 0, stream>>>(ca);

    // QKV: ring (global_load_lds), grid 24x32 = 768 = 3 full rounds
    gemm_ring<0, 128><<<dim3(3 * H / 128, M / 256), dim3(512), 0, stream>>>(
        Xb, Wqkvb, Qb, Kb, Vt, nullptr, nullptr, M, 3 * H, H);

    attn_kernel<<<dim3(256), dim3(256), 0, stream>>>(Qb, Kb, Vt, Attb);

    // Wo: reg-staged (A/B test), grid 8x32 = 256; draft stored bf16
    gemm_rs<1><<<dim3(H / 128, M / 256), dim3(512), 0, stream>>>(
        Attb, Wob, x, draftb, nullptr, nullptr, M, H, H);

    ln_kernel<<<dim3(M), dim3(256), 0, stream>>>(draftb, lnw, lnb, hlnb);

    // W1: ring BN=64, grid 8x32 = 256 (was 128 half-idle)
    gemm_ring<2, 64><<<dim3(Hh / 64, M / 256), dim3(512), 0, stream>>>(
        hlnb, W1b, nullptr, nullptr, nullptr, Gb, b1, M, Hh, H);

    // W2: reg-staged, grid 8x32 = 256
    gemm_rs<3><<<dim3(H / 128, M / 256), dim3(512), 0, stream>>>(
        Gb, W2b, nullptr, draftb, b2, outp, M, H, Hh);
}

// Round 6
// 168.751 us; speedup vs baseline: 1.3016x; 1.3016x over previous
//
#include <hip/hip_runtime.h>
#include <stdint.h>

typedef unsigned short u16;
typedef __bf16 bfx8 __attribute__((ext_vector_type(8)));
typedef float f32x4 __attribute__((ext_vector_type(4)));

__device__ __forceinline__ u16 f2bf(float x) {
    unsigned int u = __float_as_uint(x);
    u += 0x7fffu + ((u >> 16) & 1u);
    return (u16)(u >> 16);
}
__device__ __forceinline__ float bf2f(u16 v) {
    return __uint_as_float(((unsigned)v) << 16);
}

__device__ __forceinline__ void async16(const void* g, void* l) {
    __builtin_amdgcn_global_load_lds(
        (const __attribute__((address_space(1))) unsigned int*)(uintptr_t)g,
        (__attribute__((address_space(3))) unsigned int*)(unsigned int)(uintptr_t)l,
        16, 0, 0);
}

#define S_BARRIER() asm volatile("s_barrier" ::: "memory")
#define WAIT_VM6() asm volatile("s_waitcnt vmcnt(6)" ::: "memory")
#define WAIT_VM5() asm volatile("s_waitcnt vmcnt(5)" ::: "memory")
#define WAIT_VM0() asm volatile("s_waitcnt vmcnt(0)" ::: "memory")

// ---------------------------------------------------------------------------
// fused cast: 7 segments of f32 -> bf16, 8 elems/thread, one launch
// ---------------------------------------------------------------------------
struct CastArgs {
    const float* src[7];
    u16* dst[7];
    int nblk[7];
};
__global__ __launch_bounds__(256) void cast_all(CastArgs a) {
    int b = blockIdx.x, seg = 0;
    while (b >= a.nblk[seg]) { b -= a.nblk[seg]; ++seg; }
    int i = b * 256 + threadIdx.x;
    const float4* p = (const float4*)(a.src[seg] + (size_t)i * 8);
    float4 x = p[0], y = p[1];
    ushort4 o0, o1;
    o0.x = f2bf(x.x); o0.y = f2bf(x.y); o0.z = f2bf(x.z); o0.w = f2bf(x.w);
    o1.x = f2bf(y.x); o1.y = f2bf(y.y); o1.z = f2bf(y.z); o1.w = f2bf(y.w);
    ushort4* q = (ushort4*)(a.dst[seg] + (size_t)i * 8);
    q[0] = o0; q[1] = o1;
}

// ---------------------------------------------------------------------------
// RING GEMM (global_load_lds transport): C = A[M,K]*Bw[N,K]^T  (bf16, f32 acc)
// BM=256, BN=BNv(128|64), BK=64, 8 waves (4M x 2N), wave tile 64 x BNv/2.
// 3-deep LDS ring, depth-2 prefetch, counted vmcnt(6|5), raw s_barrier.
// 1D grid with bijective XCD-chunked swizzle: XCD x owns contiguous
// row-bands (A panel L2-resident per XCD); requires gridDim.x % 8 == 0.
// EPI 0 (BNv=128): QKV split epilogue (Q rows / K rows / V^T)
// EPI 1 (BNv=128): draftb = bf16(bf2f(resb) + C)
// EPI 2 (BNv=64):  outb = bf16(gelu(C + bias))
// EPI 3 (BNv=128): outf = bf2f(draftb) + C + bias
// ---------------------------------------------------------------------------
template <int EPI, int BNv>
__global__ __launch_bounds__(512, 2)
void gemm_ring(const u16* __restrict__ A, const u16* __restrict__ Bw,
               u16* __restrict__ outq, u16* __restrict__ outk,
               u16* __restrict__ vt, u16* __restrict__ outb,
               const float* __restrict__ bias, const u16* __restrict__ resb,
               u16* __restrict__ draftb, float* __restrict__ outf,
               int M, int N, int K, int ncol) {
    constexpr int NF = BNv / 32;           // B frags per wave (4 or 2)
    constexpr int BU = BNv / 64;           // B stage units per thread (2 or 1)
    constexpr int TS = 32768 + BNv * 128;  // ring tile stride bytes
    __shared__ __align__(1024) unsigned char lds[3 * TS];
    const int t = threadIdx.x;
    const int lane = t & 63, w = t >> 6;
    const int laneR = lane & 15, laneK = lane >> 4;
    const int wr = w >> 1, wc = w & 1;
    // XCD-chunked bijective swizzle (gridDim.x % 8 == 0)
    const int b = blockIdx.x;
    const int cpx = gridDim.x >> 3;
    const int swz = (b & 7) * cpx + (b >> 3);
    const int row0 = (swz / ncol) * 256, col0 = (swz % ncol) * BNv;
    const int nt = K >> 6;

    f32x4 acc[4][NF] = {};

    const u16* srcA[4];
    const u16* srcB[BU];
    unsigned dA[4], dB[BU];
#pragma unroll
    for (int i = 0; i < 4; ++i) {
        int li = i * 512 + t;
        int row = li >> 3, ko = li & 7;
        srcA[i] = A + (size_t)(row0 + row) * K + (ko ^ (row & 7)) * 8;
        dA[i] = li * 16;
    }
#pragma unroll
    for (int i = 0; i < BU; ++i) {
        int li = i * 512 + t;
        int row = li >> 3, ko = li & 7;
        srcB[i] = Bw + (size_t)(col0 + row) * K + (ko ^ (row & 7)) * 8;
        dB[i] = 32768 + li * 16;
    }

    auto stage = [&](int rb, int tk, int h) {
        unsigned char* base = lds + rb * TS;
        const int o = tk * 64;
        if (h == 0) {
            async16(srcA[0] + o, base + dA[0]);
            async16(srcA[1] + o, base + dA[1]);
            async16(srcB[0] + o, base + dB[0]);
        } else {
            async16(srcA[2] + o, base + dA[2]);
            async16(srcA[3] + o, base + dA[3]);
            if constexpr (BU == 2) async16(srcB[1] + o, base + dB[1]);
        }
    };

    stage(0, 0, 0); stage(0, 0, 1);
    stage(1, 1, 0); stage(1, 1, 1);

    for (int tk = 0; tk < nt; ++tk) {
        unsigned char* bufA = lds + (tk % 3) * TS;
        unsigned char* bufB = bufA + 32768;
        if (tk + 1 < nt) {
            if constexpr (BU == 2) { WAIT_VM6(); } else { WAIT_VM5(); }
        } else { WAIT_VM0(); }
        S_BARRIER();
        const bool pf = (tk + 2 < nt);
        const int nb = (tk + 2) % 3;
#pragma unroll
        for (int ks = 0; ks < 2; ++ks) {
            bfx8 af[4], bf[NF];
#pragma unroll
            for (int m = 0; m < 4; ++m) {
                int r = wr * 64 + m * 16 + laneR;
                int phys = (ks * 4 + laneK) ^ (r & 7);
                af[m] = *(const bfx8*)(bufA + r * 128 + phys * 16);
            }
#pragma unroll
            for (int n = 0; n < NF; ++n) {
                int r = wc * (BNv / 2) + n * 16 + laneR;
                int phys = (ks * 4 + laneK) ^ (r & 7);
                bf[n] = *(const bfx8*)(bufB + r * 128 + phys * 16);
            }
            if (pf) stage(nb, tk + 2, ks);
            S_BARRIER();
            __builtin_amdgcn_s_setprio(1);
#pragma unroll
            for (int m = 0; m < 4; ++m)
#pragma unroll
                for (int n = 0; n < NF; ++n)
                    acc[m][n] = __builtin_amdgcn_mfma_f32_16x16x32_bf16(
                        af[m], bf[n], acc[m][n], 0, 0, 0);
            __builtin_amdgcn_s_setprio(0);
            S_BARRIER();
        }
    }

#pragma unroll
    for (int m = 0; m < 4; ++m) {
        const int gr0 = row0 + wr * 64 + m * 16 + laneK * 4;
#pragma unroll
        for (int n = 0; n < NF; ++n) {
            const int gc = col0 + wc * (BNv / 2) + n * 16 + laneR;
            if constexpr (EPI == 0) {
                if (col0 < 1024) {
#pragma unroll
                    for (int r = 0; r < 4; ++r)
                        outq[(size_t)(gr0 + r) * 1024 + gc] = f2bf(acc[m][n][r]);
                } else if (col0 < 2048) {
#pragma unroll
                    for (int r = 0; r < 4; ++r)
                        outk[(size_t)(gr0 + r) * 1024 + (gc - 1024)] = f2bf(acc[m][n][r]);
                } else {
                    ushort4 o4;
                    o4.x = f2bf(acc[m][n][0]); o4.y = f2bf(acc[m][n][1]);
                    o4.z = f2bf(acc[m][n][2]); o4.w = f2bf(acc[m][n][3]);
                    *(ushort4*)(vt + (((size_t)(gr0 >> 12)) * 1024 + (gc - 2048)) * 4096 +
                                (gr0 & 4095)) = o4;
                }
            } else if constexpr (EPI == 1) {
#pragma unroll
                for (int r = 0; r < 4; ++r) {
                    size_t idx = (size_t)(gr0 + r) * N + gc;
                    draftb[idx] = f2bf(bf2f(resb[idx]) + acc[m][n][r]);
                }
            } else if constexpr (EPI == 2) {
#pragma unroll
                for (int r = 0; r < 4; ++r) {
                    float xx = acc[m][n][r] + bias[gc];
                    outb[(size_t)(gr0 + r) * N + gc] =
                        f2bf(xx * 0.5f * (1.0f + erff(xx * 0.70710678118654752f)));
                }
            } else {
#pragma unroll
                for (int r = 0; r < 4; ++r) {
                    size_t idx = (size_t)(gr0 + r) * N + gc;
                    outf[idx] = bf2f(draftb[idx]) + acc[m][n][r] + bias[gc];
                }
            }
        }
    }
}

// ---------------------------------------------------------------------------
// banded attention: WINDOW=32, 32-query tiles, 64-key band [i0-32, i0+31]
// XCD-chunked tile swizzle (neighboring tiles share 32 K/V rows -> L2 hits)
// ---------------------------------------------------------------------------
__global__ __launch_bounds__(256, 2)
void attn_kernel(const u16* __restrict__ Q, const u16* __restrict__ K,
                 const u16* __restrict__ vt, u16* __restrict__ O) {
    constexpr int H = 1024, S = 4096;
    const int t = threadIdx.x, lane = t & 63, w = t >> 6;
    const int laneR = lane & 15, laneK = lane >> 4;
    const int bb = blockIdx.x;
    const int tile = (bb & 7) * 32 + (bb >> 3);   // bijective: 256 = 8 * 32
    const int batch = tile >> 7;
    const int i0 = (tile & 127) * 32;
    const size_t base = (size_t)batch * S * H;

    __shared__ __align__(16) float S4[4][32][64];
    __shared__ __align__(16) u16 P[32][72];

    f32x4 sc[2][4] = {};
    for (int h = w * 256; h < w * 256 + 256; h += 32) {
        bfx8 qa[2];
#pragma unroll
        for (int m = 0; m < 2; ++m) {
            size_t row = (size_t)(i0 + m * 16 + laneR);
            qa[m] = *(const bfx8*)(Q + base + row * H + h + laneK * 8);
        }
        bfx8 kb[4];
#pragma unroll
        for (int n = 0; n < 4; ++n) {
            int j = i0 - 32 + n * 16 + laneR;
            int jc = j < 0 ? 0 : j;
            kb[n] = *(const bfx8*)(K + base + (size_t)jc * H + h + laneK * 8);
        }
#pragma unroll
        for (int m = 0; m < 2; ++m)
#pragma unroll
            for (int n = 0; n < 4; ++n)
                sc[m][n] = __builtin_amdgcn_mfma_f32_16x16x32_bf16(
                    qa[m], kb[n], sc[m][n], 0, 0, 0);
    }
#pragma unroll
    for (int m = 0; m < 2; ++m)
#pragma unroll
        for (int n = 0; n < 4; ++n)
#pragma unroll
            for (int r = 0; r < 4; ++r)
                S4[w][m * 16 + laneK * 4 + r][n * 16 + laneR] = sc[m][n][r];
    __syncthreads();

    {
        int q = t >> 3;
        int c0 = (t & 7) * 8;
        int lo = q + 1;
        if (32 - i0 > lo) lo = 32 - i0;
        int hi = q + 32;
        float vals[8];
        float mx = -1e30f;
#pragma unroll
        for (int c = 0; c < 8; ++c) {
            int cc = c0 + c;
            float v = (S4[0][q][cc] + S4[1][q][cc] + S4[2][q][cc] + S4[3][q][cc]) * 0.03125f;
            bool valid = (cc >= lo) && (cc <= hi);
            vals[c] = valid ? v : -1e30f;
            if (vals[c] > mx) mx = vals[c];
        }
#pragma unroll
        for (int d = 1; d < 8; d <<= 1) {
            float o = __shfl_xor(mx, d);
            if (o > mx) mx = o;
        }
        float sum = 0.f;
        float es[8];
#pragma unroll
        for (int c = 0; c < 8; ++c) {
            es[c] = (vals[c] > -1e29f) ? __expf(vals[c] - mx) : 0.f;
            sum += es[c];
        }
#pragma unroll
        for (int d = 1; d < 8; d <<= 1) sum += __shfl_xor(sum, d);
        float inv = 1.0f / sum;
#pragma unroll
        for (int c = 0; c < 8; ++c) P[q][c0 + c] = f2bf(es[c] * inv);
    }
    __syncthreads();

    for (int nc = 0; nc < 4; ++nc) {
        int ncol = w * 256 + nc * 64;
        f32x4 o[2][4] = {};
#pragma unroll
        for (int ks = 0; ks < 2; ++ks) {
            bfx8 pa[2];
#pragma unroll
            for (int m = 0; m < 2; ++m)
                pa[m] = *(const bfx8*)(&P[m * 16 + laneR][ks * 32 + laneK * 8]);
            int t0 = i0 - 32 + ks * 32 + laneK * 8;
            if (t0 < 0) t0 = 0;
#pragma unroll
            for (int n = 0; n < 4; ++n) {
                int c = ncol + n * 16 + laneR;
                bfx8 vb = *(const bfx8*)(vt + ((size_t)batch * 1024 + c) * 4096 + t0);
#pragma unroll
                for (int m = 0; m < 2; ++m)
                    o[m][n] = __builtin_amdgcn_mfma_f32_16x16x32_bf16(
                        pa[m], vb, o[m][n], 0, 0, 0);
            }
        }
#pragma unroll
        for (int m = 0; m < 2; ++m)
#pragma unroll
            for (int n = 0; n < 4; ++n)
#pragma unroll
                for (int r = 0; r < 4; ++r) {
                    size_t row = (size_t)(i0 + m * 16 + laneK * 4 + r);
                    O[base + row * H + ncol + n * 16 + laneR] = f2bf(o[m][n][r]);
                }
    }
}

// ---------------------------------------------------------------------------
// LayerNorm over H=1024, one block per row, bf16 in -> bf16 out
// ---------------------------------------------------------------------------
__global__ __launch_bounds__(256)
void ln_kernel(const u16* __restrict__ xb, const float* __restrict__ gw,
               const float* __restrict__ gb, u16* __restrict__ out) {
    const int row = blockIdx.x, t = threadIdx.x;
    const ushort4 dv = ((const ushort4*)(xb + (size_t)row * 1024))[t];
    float4 v;
    v.x = bf2f(dv.x); v.y = bf2f(dv.y); v.z = bf2f(dv.z); v.w = bf2f(dv.w);
    float s = v.x + v.y + v.z + v.w;
    float s2 = v.x * v.x + v.y * v.y + v.z * v.z + v.w * v.w;
#pragma unroll
    for (int d = 1; d < 64; d <<= 1) {
        s += __shfl_xor(s, d);
        s2 += __shfl_xor(s2, d);
    }
    __shared__ float red[8];
    int lane = t & 63, wv = t >> 6;
    if (lane == 0) { red[wv] = s; red[4 + wv] = s2; }
    __syncthreads();
    float S1 = red[0] + red[1] + red[2] + red[3];
    float S2 = red[4] + red[5] + red[6] + red[7];
    float mu = S1 * (1.0f / 1024.0f);
    float var = S2 * (1.0f / 1024.0f) - mu * mu;
    float rstd = rsqrtf(var + 1e-5f);
    const float4 wv4 = ((const float4*)gw)[t];
    const float4 bv4 = ((const float4*)gb)[t];
    ushort4 o;
    o.x = f2bf((v.x - mu) * rstd * wv4.x + bv4.x);
    o.y = f2bf((v.y - mu) * rstd * wv4.y + bv4.y);
    o.z = f2bf((v.z - mu) * rstd * wv4.z + bv4.z);
    o.w = f2bf((v.w - mu) * rstd * wv4.w + bv4.w);
    ((ushort4*)(out + (size_t)row * 1024))[t] = o;
}

// ---------------------------------------------------------------------------
extern "C" void kernel_launch(void* const* d_in, const int* in_sizes, int n_in,
                              void* d_out, int out_size, void* d_ws, size_t ws_size,
                              hipStream_t stream) {
    const float* x   = (const float*)d_in[0];
    const float* Wq  = (const float*)d_in[1];
    const float* Wk  = (const float*)d_in[2];
    const float* Wv  = (const float*)d_in[3];
    const float* Wo  = (const float*)d_in[4];
    const float* lnw = (const float*)d_in[5];
    const float* lnb = (const float*)d_in[6];
    const float* W1  = (const float*)d_in[7];
    const float* b1  = (const float*)d_in[8];
    const float* W2  = (const float*)d_in[9];
    const float* b2  = (const float*)d_in[10];
    (void)in_sizes; (void)n_in; (void)out_size; (void)ws_size;

    const int M = 8192, H = 1024, Hh = 512;

    char* ws = (char*)d_ws;
    size_t off = 0;
    auto alloc = [&](size_t bytes) {
        char* p = ws + off;
        off += (bytes + 255) & ~(size_t)255;
        return p;
    };
    u16* Xb     = (u16*)alloc((size_t)M * H * 2);      // kept (residual for Wo)
    u16* Wqkvb  = (u16*)alloc((size_t)3 * H * H * 2);
    u16* Wob    = (u16*)alloc((size_t)H * H * 2);
    u16* W1b    = (u16*)alloc((size_t)Hh * H * 2);
    u16* W2b    = (u16*)alloc((size_t)H * Hh * 2);
    u16* Qb     = (u16*)alloc((size_t)M * H * 2);      // reused as hlnb
    u16* Kb     = (u16*)alloc((size_t)M * H * 2);      // reused as Gb
    u16* Vt     = (u16*)alloc((size_t)M * H * 2);
    u16* draftb = (u16*)alloc((size_t)M * H * 2);
    u16* Attb   = (u16*)alloc((size_t)M * H * 2);
    u16* hlnb = Qb;
    u16* Gb   = Kb;
    float* outp = (float*)d_out;

    CastArgs ca;
    ca.src[0] = x;  ca.dst[0] = Xb;                        ca.nblk[0] = (M * H / 8) / 256;
    ca.src[1] = Wq; ca.dst[1] = Wqkvb;                     ca.nblk[1] = (H * H / 8) / 256;
    ca.src[2] = Wk; ca.dst[2] = Wqkvb + (size_t)H * H;     ca.nblk[2] = (H * H / 8) / 256;
    ca.src[3] = Wv; ca.dst[3] = Wqkvb + (size_t)2 * H * H; ca.nblk[3] = (H * H / 8) / 256;
    ca.src[4] = Wo; ca.dst[4] = Wob;                       ca.nblk[4] = (H * H / 8) / 256;
    ca.src[5] = W1; ca.dst[5] = W1b;                       ca.nblk[5] = (Hh * H / 8) / 256;
    ca.src[6] = W2; ca.dst[6] = W2b;                       ca.nblk[6] = (H * Hh / 8) / 256;
    int totblk = 0;
    for (int i = 0; i < 7; ++i) totblk += ca.nblk[i];
    cast_all<<<dim3(totblk), dim3(256), 0, stream>>>(ca);

    // QKV: grid 768 (1D), ncol=24; XCD-chunked swizzle
    gemm_ring<0, 128><<<dim3(768), dim3(512), 0, stream>>>(
        Xb, Wqkvb, Qb, Kb, Vt, nullptr, nullptr, nullptr, nullptr, nullptr,
        M, 3 * H, H, 24);

    attn_kernel<<<dim3(256), dim3(256), 0, stream>>>(Qb, Kb, Vt, Attb);

    // Wo: grid 256, ncol=8; draftb = bf16(Xb + C)
    gemm_ring<1, 128><<<dim3(256), dim3(512), 0, stream>>>(
        Attb, Wob, nullptr, nullptr, nullptr, nullptr, nullptr, Xb, draftb, nullptr,
        M, H, H, 8);

    ln_kernel<<<dim3(M), dim3(256), 0, stream>>>(draftb, lnw, lnb, hlnb);

    // W1: BN=64, grid 256, ncol=8; Gb = gelu(C + b1)
    gemm_ring<2, 64><<<dim3(256), dim3(512), 0, stream>>>(
        hlnb, W1b, nullptr, nullptr, nullptr, Gb, b1, nullptr, nullptr, nullptr,
        M, Hh, H, 8);

    // W2: grid 256, ncol=8, K=512; out = draftb + C + b2
    gemm_ring<3, 128><<<dim3(256), dim3(512), 0, stream>>>(
        Gb, W2b, nullptr, nullptr, nullptr, nullptr, b2, nullptr, draftb, outp,
        M, H, Hh, 8);
}

// Round 8
// 167.925 us; speedup vs baseline: 1.3080x; 1.0049x over previous
//
#include <hip/hip_runtime.h>
#include <stdint.h>

typedef unsigned short u16;
typedef __bf16 bfx8 __attribute__((ext_vector_type(8)));
typedef float f32x4 __attribute__((ext_vector_type(4)));

__device__ __forceinline__ u16 f2bf(float x) {
    unsigned int u = __float_as_uint(x);
    u += 0x7fffu + ((u >> 16) & 1u);
    return (u16)(u >> 16);
}
__device__ __forceinline__ float bf2f(u16 v) {
    return __uint_as_float(((unsigned)v) << 16);
}

__device__ __forceinline__ void async16(const void* g, void* l) {
    __builtin_amdgcn_global_load_lds(
        (const __attribute__((address_space(1))) unsigned int*)(uintptr_t)g,
        (__attribute__((address_space(3))) unsigned int*)(unsigned int)(uintptr_t)l,
        16, 0, 0);
}

#define S_BARRIER() asm volatile("s_barrier" ::: "memory")
#define WAIT_VM6() asm volatile("s_waitcnt vmcnt(6)" ::: "memory")
#define WAIT_VM5() asm volatile("s_waitcnt vmcnt(5)" ::: "memory")
#define WAIT_VM2() asm volatile("s_waitcnt vmcnt(2)" ::: "memory")
#define WAIT_VM0() asm volatile("s_waitcnt vmcnt(0)" ::: "memory")

// ---------------------------------------------------------------------------
// fused cast: 7 segments of f32 -> bf16, 8 elems/thread, one launch
// ---------------------------------------------------------------------------
struct CastArgs {
    const float* src[7];
    u16* dst[7];
    int nblk[7];
};
__global__ __launch_bounds__(256) void cast_all(CastArgs a) {
    int b = blockIdx.x, seg = 0;
    while (b >= a.nblk[seg]) { b -= a.nblk[seg]; ++seg; }
    int i = b * 256 + threadIdx.x;
    const float4* p = (const float4*)(a.src[seg] + (size_t)i * 8);
    float4 x = p[0], y = p[1];
    ushort4 o0, o1;
    o0.x = f2bf(x.x); o0.y = f2bf(x.y); o0.z = f2bf(x.z); o0.w = f2bf(x.w);
    o1.x = f2bf(y.x); o1.y = f2bf(y.y); o1.z = f2bf(y.z); o1.w = f2bf(y.w);
    ushort4* q = (ushort4*)(a.dst[seg] + (size_t)i * 8);
    q[0] = o0; q[1] = o1;
}

// ---------------------------------------------------------------------------
// QKV2: 256x256 fine-phase GEMM. C[M,3072] = A[M,K]*Bw[3072,K]^T.
// 8 waves (2M x 4N), BK=64. LDS 2 x 64KB dbuf; rows of 128B x 8 chunks,
// phys chunk = ko ^ (row&7) (0-conflict layout).
// Wave->row mapping aligned with stage units (ROUND-8 FIX):
//   A row = half*128 + wm*64 + m*16 + laneR
// so P1/P3 (half0) read ONLY u0 = A rows 0-127, P2/P4 (half1) read ONLY
// u1 = A rows 128-255; B (u2: rows 0-127, u3: 128-255) read in P1/P3.
// Stage units (2 async16/thread): P1:u0(t+1) P2:u2(t+1) P3:u3(t+1) P4:u1(t+1).
// Waits (FIFO ledger, race-free):
//   end-P1(t) vm2: outstanding {u1(t), u0(t+1)} -> drains u1(t) (read P2)
//   end-P4(t) vm2: outstanding {u0,u2,u3,u1}(t+1) -> drains u0,u2,u3 (read P1)
// Tail tile: no stages; end-P1 vm0 drains u1(last).
// Epilogue: cols 0-1023 -> Q, 1024-2047 -> K, 2048-3071 -> V^T.
// ---------------------------------------------------------------------------
__global__ __launch_bounds__(512, 2)
void gemm_qkv2(const u16* __restrict__ A, const u16* __restrict__ Bw,
               u16* __restrict__ outq, u16* __restrict__ outk,
               u16* __restrict__ vt, int K) {
    __shared__ __align__(1024) unsigned char lds[131072];
    const int t = threadIdx.x;
    const int lane = t & 63, w = t >> 6;
    const int laneR = lane & 15, laneK = lane >> 4;
    const int wm = w >> 2, wn = w & 3;
    const int b = blockIdx.x;
    const int swz = (b & 7) * 48 + (b >> 3);   // bijective: 384 = 8*48
    const int row0 = (swz / 12) * 256;
    const int col0 = (swz % 12) * 256;
    const int nt = K >> 6;

    // unit pointers: u0/u1 = A row-halves, u2/u3 = B row-halves
    const u16* srcU[4][2];
    unsigned dstU[4][2];
#pragma unroll
    for (int u = 0; u < 4; ++u)
#pragma unroll
        for (int j = 0; j < 2; ++j) {
            int c = ((u & 1) ? 1024 : 0) + j * 512 + t;   // chunk in region
            int row = c >> 3;
            int ko = (c & 7) ^ (row & 7);
            if (u < 2) srcU[u][j] = A + (size_t)(row0 + row) * K + ko * 8;
            else       srcU[u][j] = Bw + (size_t)(col0 + row) * K + ko * 8;
            dstU[u][j] = (u >= 2 ? 32768u : 0u) + (unsigned)c * 16u;
        }

#define QSTAGE(U, D, TK)                                                      \
    async16(srcU[U][0] + (TK) * 64, lds + (D) + dstU[U][0]);                  \
    async16(srcU[U][1] + (TK) * 64, lds + (D) + dstU[U][1]);

    f32x4 acc[8][4] = {};
    bfx8 af[4], bf[4];

#define QLDA(D, KS, H)                                                        \
    _Pragma("unroll") for (int m = 0; m < 4; ++m) {                           \
        int r = (H) * 128 + wm * 64 + m * 16 + laneR;                         \
        int ph = ((KS) * 4 + laneK) ^ (r & 7);                                \
        af[m] = *(const bfx8*)(lds + (D) + r * 128 + ph * 16);                \
    }
#define QLDB(D, KS)                                                           \
    _Pragma("unroll") for (int n = 0; n < 4; ++n) {                           \
        int rb = wn * 64 + n * 16 + laneR;                                    \
        int ph = ((KS) * 4 + laneK) ^ (rb & 7);                               \
        bf[n] = *(const bfx8*)(lds + (D) + 32768u + rb * 128 + ph * 16);      \
    }
#define QMFMA(H)                                                              \
    __builtin_amdgcn_s_setprio(1);                                            \
    _Pragma("unroll") for (int m = 0; m < 4; ++m)                             \
        _Pragma("unroll") for (int n = 0; n < 4; ++n)                         \
            acc[(H) * 4 + m][n] = __builtin_amdgcn_mfma_f32_16x16x32_bf16(    \
                af[m], bf[n], acc[(H) * 4 + m][n], 0, 0, 0);                  \
    __builtin_amdgcn_s_setprio(0);

    // prologue: stage tile0 in order u0,u2,u3,u1; vm2 leaves u1(0) in flight
    QSTAGE(0, 0u, 0) QSTAGE(2, 0u, 0) QSTAGE(3, 0u, 0) QSTAGE(1, 0u, 0)
    WAIT_VM2();
    S_BARRIER();

    for (int tk = 0; tk < nt - 1; ++tk) {
        const unsigned d = (unsigned)(tk & 1) * 65536u;
        const unsigned nd = d ^ 65536u;
        const int tn = tk + 1;
        // P1 (ks0, half0: A rows 0-127 + all B)
        QLDA(d, 0, 0) QLDB(d, 0) QSTAGE(0, nd, tn)
        S_BARRIER();
        QMFMA(0)
        WAIT_VM2();        // drain u1(tk) before P2 reads it
        S_BARRIER();
        // P2 (ks0, half1: A rows 128-255)
        QLDA(d, 0, 1) QSTAGE(2, nd, tn)
        S_BARRIER();
        QMFMA(1)
        S_BARRIER();
        // P3 (ks1, half0)
        QLDA(d, 1, 0) QLDB(d, 1) QSTAGE(3, nd, tn)
        S_BARRIER();
        QMFMA(0)
        S_BARRIER();
        // P4 (ks1, half1)
        QLDA(d, 1, 1) QSTAGE(1, nd, tn)
        S_BARRIER();
        QMFMA(1)
        WAIT_VM2();        // drain u0,u2,u3(tk+1); u1(tk+1) stays in flight
        S_BARRIER();
    }
    // tail tile nt-1 (no stages)
    {
        const unsigned d = (unsigned)((nt - 1) & 1) * 65536u;
        QLDA(d, 0, 0) QLDB(d, 0)
        S_BARRIER();
        QMFMA(0)
        WAIT_VM0();        // drain u1(nt-1)
        S_BARRIER();
        QLDA(d, 0, 1)
        S_BARRIER();
        QMFMA(1)
        S_BARRIER();
        QLDA(d, 1, 0) QLDB(d, 1)
        S_BARRIER();
        QMFMA(0)
        S_BARRIER();
        QLDA(d, 1, 1)
        S_BARRIER();
        QMFMA(1)
    }

    const int colsec = col0 >> 10;   // 0=Q, 1=K, 2=V
#pragma unroll
    for (int hi = 0; hi < 2; ++hi) {
#pragma unroll
        for (int mi = 0; mi < 4; ++mi) {
            const int gr0 = row0 + hi * 128 + wm * 64 + mi * 16 + laneK * 4;
#pragma unroll
            for (int n = 0; n < 4; ++n) {
                const int gc = col0 + wn * 64 + n * 16 + laneR;
                const f32x4 a4 = acc[hi * 4 + mi][n];
                if (colsec == 0) {
#pragma unroll
                    for (int r = 0; r < 4; ++r)
                        outq[(size_t)(gr0 + r) * 1024 + gc] = f2bf(a4[r]);
                } else if (colsec == 1) {
#pragma unroll
                    for (int r = 0; r < 4; ++r)
                        outk[(size_t)(gr0 + r) * 1024 + (gc - 1024)] = f2bf(a4[r]);
                } else {
                    ushort4 o4;
                    o4.x = f2bf(a4[0]); o4.y = f2bf(a4[1]);
                    o4.z = f2bf(a4[2]); o4.w = f2bf(a4[3]);
                    *(ushort4*)(vt + (((size_t)(gr0 >> 12)) * 1024 + (gc - 2048)) * 4096 +
                                (gr0 & 4095)) = o4;
                }
            }
        }
    }
#undef QSTAGE
#undef QLDA
#undef QLDB
#undef QMFMA
}

// ---------------------------------------------------------------------------
// RING GEMM (global_load_lds, 4 barriers/tile): C = A[M,K]*Bw[N,K]^T
// BM=256, BN=BNv(128|64), BK=64, 8 waves (4M x 2N), wave tile 64 x BNv/2.
// 3-deep LDS ring, depth-2 prefetch, counted vmcnt(6|5) folded into the
// ks1 end-barrier. XCD-chunked bijective 1D grid swizzle (gridDim %8==0).
// EPI 1: draftb = bf16(bf2f(resb) + C)
// EPI 2 (BN=64): outb = bf16(gelu(C + bias))
// EPI 3: outf = bf2f(draftb) + C + bias
// ---------------------------------------------------------------------------
template <int EPI, int BNv>
__global__ __launch_bounds__(512, 2)
void gemm_ring(const u16* __restrict__ A, const u16* __restrict__ Bw,
               u16* __restrict__ outb, const float* __restrict__ bias,
               const u16* __restrict__ resb, u16* __restrict__ draftb,
               float* __restrict__ outf, int M, int N, int K, int ncol) {
    constexpr int NF = BNv / 32;
    constexpr int BU = BNv / 64;
    constexpr int TS = 32768 + BNv * 128;
    __shared__ __align__(1024) unsigned char lds[3 * TS];
    const int t = threadIdx.x;
    const int lane = t & 63, w = t >> 6;
    const int laneR = lane & 15, laneK = lane >> 4;
    const int wr = w >> 1, wc = w & 1;
    const int b = blockIdx.x;
    const int cpx = gridDim.x >> 3;
    const int swz = (b & 7) * cpx + (b >> 3);
    const int row0 = (swz / ncol) * 256, col0 = (swz % ncol) * BNv;
    const int nt = K >> 6;

    f32x4 acc[4][NF] = {};

    const u16* srcA[4];
    const u16* srcB[BU];
    unsigned dA[4], dB[BU];
#pragma unroll
    for (int i = 0; i < 4; ++i) {
        int li = i * 512 + t;
        int row = li >> 3, ko = li & 7;
        srcA[i] = A + (size_t)(row0 + row) * K + (ko ^ (row & 7)) * 8;
        dA[i] = li * 16;
    }
#pragma unroll
    for (int i = 0; i < BU; ++i) {
        int li = i * 512 + t;
        int row = li >> 3, ko = li & 7;
        srcB[i] = Bw + (size_t)(col0 + row) * K + (ko ^ (row & 7)) * 8;
        dB[i] = 32768 + li * 16;
    }

    auto stage = [&](int rb, int tk, int h) {
        unsigned char* base = lds + rb * TS;
        const int o = tk * 64;
        if (h == 0) {
            async16(srcA[0] + o, base + dA[0]);
            async16(srcA[1] + o, base + dA[1]);
            async16(srcB[0] + o, base + dB[0]);
        } else {
            async16(srcA[2] + o, base + dA[2]);
            async16(srcA[3] + o, base + dA[3]);
            if constexpr (BU == 2) async16(srcB[1] + o, base + dB[1]);
        }
    };

    // prologue: stage tiles 0,1; drain tile0 (leave tile1 in flight)
    stage(0, 0, 0); stage(0, 0, 1);
    stage(1, 1, 0); stage(1, 1, 1);
    if constexpr (BU == 2) { WAIT_VM6(); } else { WAIT_VM5(); }
    S_BARRIER();

    for (int tk = 0; tk < nt; ++tk) {
        unsigned char* bufA = lds + (tk % 3) * TS;
        unsigned char* bufB = bufA + 32768;
        const bool pf = (tk + 2 < nt);
        const int nb = (tk + 2) % 3;
#pragma unroll
        for (int ks = 0; ks < 2; ++ks) {
            bfx8 af[4], bf[NF];
#pragma unroll
            for (int m = 0; m < 4; ++m) {
                int r = wr * 64 + m * 16 + laneR;
                int phys = (ks * 4 + laneK) ^ (r & 7);
                af[m] = *(const bfx8*)(bufA + r * 128 + phys * 16);
            }
#pragma unroll
            for (int n = 0; n < NF; ++n) {
                int r = wc * (BNv / 2) + n * 16 + laneR;
                int phys = (ks * 4 + laneK) ^ (r & 7);
                bf[n] = *(const bfx8*)(bufB + r * 128 + phys * 16);
            }
            if (pf) stage(nb, tk + 2, ks);
            S_BARRIER();
            __builtin_amdgcn_s_setprio(1);
#pragma unroll
            for (int m = 0; m < 4; ++m)
#pragma unroll
                for (int n = 0; n < NF; ++n)
                    acc[m][n] = __builtin_amdgcn_mfma_f32_16x16x32_bf16(
                        af[m], bf[n], acc[m][n], 0, 0, 0);
            __builtin_amdgcn_s_setprio(0);
            if (ks == 1) {
                if (pf) {
                    if constexpr (BU == 2) { WAIT_VM6(); } else { WAIT_VM5(); }
                } else {
                    WAIT_VM0();
                }
            }
            S_BARRIER();
        }
    }

#pragma unroll
    for (int m = 0; m < 4; ++m) {
        const int gr0 = row0 + wr * 64 + m * 16 + laneK * 4;
#pragma unroll
        for (int n = 0; n < NF; ++n) {
            const int gc = col0 + wc * (BNv / 2) + n * 16 + laneR;
            if constexpr (EPI == 1) {
#pragma unroll
                for (int r = 0; r < 4; ++r) {
                    size_t idx = (size_t)(gr0 + r) * N + gc;
                    draftb[idx] = f2bf(bf2f(resb[idx]) + acc[m][n][r]);
                }
            } else if constexpr (EPI == 2) {
#pragma unroll
                for (int r = 0; r < 4; ++r) {
                    float xx = acc[m][n][r] + bias[gc];
                    outb[(size_t)(gr0 + r) * N + gc] =
                        f2bf(xx * 0.5f * (1.0f + erff(xx * 0.70710678118654752f)));
                }
            } else {
#pragma unroll
                for (int r = 0; r < 4; ++r) {
                    size_t idx = (size_t)(gr0 + r) * N + gc;
                    outf[idx] = bf2f(draftb[idx]) + acc[m][n][r] + bias[gc];
                }
            }
        }
    }
}

// ---------------------------------------------------------------------------
// banded attention: WINDOW=32, 32-query tiles, 64-key band [i0-32, i0+31]
// ---------------------------------------------------------------------------
__global__ __launch_bounds__(256, 2)
void attn_kernel(const u16* __restrict__ Q, const u16* __restrict__ K,
                 const u16* __restrict__ vt, u16* __restrict__ O) {
    constexpr int H = 1024, S = 4096;
    const int t = threadIdx.x, lane = t & 63, w = t >> 6;
    const int laneR = lane & 15, laneK = lane >> 4;
    const int bb = blockIdx.x;
    const int tile = (bb & 7) * 32 + (bb >> 3);
    const int batch = tile >> 7;
    const int i0 = (tile & 127) * 32;
    const size_t base = (size_t)batch * S * H;

    __shared__ __align__(16) float S4[4][32][64];
    __shared__ __align__(16) u16 P[32][72];

    f32x4 sc[2][4] = {};
    for (int h = w * 256; h < w * 256 + 256; h += 32) {
        bfx8 qa[2];
#pragma unroll
        for (int m = 0; m < 2; ++m) {
            size_t row = (size_t)(i0 + m * 16 + laneR);
            qa[m] = *(const bfx8*)(Q + base + row * H + h + laneK * 8);
        }
        bfx8 kb[4];
#pragma unroll
        for (int n = 0; n < 4; ++n) {
            int j = i0 - 32 + n * 16 + laneR;
            int jc = j < 0 ? 0 : j;
            kb[n] = *(const bfx8*)(K + base + (size_t)jc * H + h + laneK * 8);
        }
#pragma unroll
        for (int m = 0; m < 2; ++m)
#pragma unroll
            for (int n = 0; n < 4; ++n)
                sc[m][n] = __builtin_amdgcn_mfma_f32_16x16x32_bf16(
                    qa[m], kb[n], sc[m][n], 0, 0, 0);
    }
#pragma unroll
    for (int m = 0; m < 2; ++m)
#pragma unroll
        for (int n = 0; n < 4; ++n)
#pragma unroll
            for (int r = 0; r < 4; ++r)
                S4[w][m * 16 + laneK * 4 + r][n * 16 + laneR] = sc[m][n][r];
    __syncthreads();

    {
        int q = t >> 3;
        int c0 = (t & 7) * 8;
        int lo = q + 1;
        if (32 - i0 > lo) lo = 32 - i0;
        int hi = q + 32;
        float vals[8];
        float mx = -1e30f;
#pragma unroll
        for (int c = 0; c < 8; ++c) {
            int cc = c0 + c;
            float v = (S4[0][q][cc] + S4[1][q][cc] + S4[2][q][cc] + S4[3][q][cc]) * 0.03125f;
            bool valid = (cc >= lo) && (cc <= hi);
            vals[c] = valid ? v : -1e30f;
            if (vals[c] > mx) mx = vals[c];
        }
#pragma unroll
        for (int d = 1; d < 8; d <<= 1) {
            float o = __shfl_xor(mx, d);
            if (o > mx) mx = o;
        }
        float sum = 0.f;
        float es[8];
#pragma unroll
        for (int c = 0; c < 8; ++c) {
            es[c] = (vals[c] > -1e29f) ? __expf(vals[c] - mx) : 0.f;
            sum += es[c];
        }
#pragma unroll
        for (int d = 1; d < 8; d <<= 1) sum += __shfl_xor(sum, d);
        float inv = 1.0f / sum;
#pragma unroll
        for (int c = 0; c < 8; ++c) P[q][c0 + c] = f2bf(es[c] * inv);
    }
    __syncthreads();

    for (int nc = 0; nc < 4; ++nc) {
        int ncol = w * 256 + nc * 64;
        f32x4 o[2][4] = {};
#pragma unroll
        for (int ks = 0; ks < 2; ++ks) {
            bfx8 pa[2];
#pragma unroll
            for (int m = 0; m < 2; ++m)
                pa[m] = *(const bfx8*)(&P[m * 16 + laneR][ks * 32 + laneK * 8]);
            int t0 = i0 - 32 + ks * 32 + laneK * 8;
            if (t0 < 0) t0 = 0;
#pragma unroll
            for (int n = 0; n < 4; ++n) {
                int c = ncol + n * 16 + laneR;
                bfx8 vb = *(const bfx8*)(vt + ((size_t)batch * 1024 + c) * 4096 + t0);
#pragma unroll
                for (int m = 0; m < 2; ++m)
                    o[m][n] = __builtin_amdgcn_mfma_f32_16x16x32_bf16(
                        pa[m], vb, o[m][n], 0, 0, 0);
            }
        }
#pragma unroll
        for (int m = 0; m < 2; ++m)
#pragma unroll
            for (int n = 0; n < 4; ++n)
#pragma unroll
                for (int r = 0; r < 4; ++r) {
                    size_t row = (size_t)(i0 + m * 16 + laneK * 4 + r);
                    O[base + row * H + ncol + n * 16 + laneR] = f2bf(o[m][n][r]);
                }
    }
}

// ---------------------------------------------------------------------------
// LayerNorm over H=1024, one block per row, bf16 in -> bf16 out
// ---------------------------------------------------------------------------
__global__ __launch_bounds__(256)
void ln_kernel(const u16* __restrict__ xb, const float* __restrict__ gw,
               const float* __restrict__ gb, u16* __restrict__ out) {
    const int row = blockIdx.x, t = threadIdx.x;
    const ushort4 dv = ((const ushort4*)(xb + (size_t)row * 1024))[t];
    float4 v;
    v.x = bf2f(dv.x); v.y = bf2f(dv.y); v.z = bf2f(dv.z); v.w = bf2f(dv.w);
    float s = v.x + v.y + v.z + v.w;
    float s2 = v.x * v.x + v.y * v.y + v.z * v.z + v.w * v.w;
#pragma unroll
    for (int d = 1; d < 64; d <<= 1) {
        s += __shfl_xor(s, d);
        s2 += __shfl_xor(s2, d);
    }
    __shared__ float red[8];
    int lane = t & 63, wv = t >> 6;
    if (lane == 0) { red[wv] = s; red[4 + wv] = s2; }
    __syncthreads();
    float S1 = red[0] + red[1] + red[2] + red[3];
    float S2 = red[4] + red[5] + red[6] + red[7];
    float mu = S1 * (1.0f / 1024.0f);
    float var = S2 * (1.0f / 1024.0f) - mu * mu;
    float rstd = rsqrtf(var + 1e-5f);
    const float4 wv4 = ((const float4*)gw)[t];
    const float4 bv4 = ((const float4*)gb)[t];
    ushort4 o;
    o.x = f2bf((v.x - mu) * rstd * wv4.x + bv4.x);
    o.y = f2bf((v.y - mu) * rstd * wv4.y + bv4.y);
    o.z = f2bf((v.z - mu) * rstd * wv4.z + bv4.z);
    o.w = f2bf((v.w - mu) * rstd * wv4.w + bv4.w);
    ((ushort4*)(out + (size_t)row * 1024))[t] = o;
}

// ---------------------------------------------------------------------------
extern "C" void kernel_launch(void* const* d_in, const int* in_sizes, int n_in,
                              void* d_out, int out_size, void* d_ws, size_t ws_size,
                              hipStream_t stream) {
    const float* x   = (const float*)d_in[0];
    const float* Wq  = (const float*)d_in[1];
    const float* Wk  = (const float*)d_in[2];
    const float* Wv  = (const float*)d_in[3];
    const float* Wo  = (const float*)d_in[4];
    const float* lnw = (const float*)d_in[5];
    const float* lnb = (const float*)d_in[6];
    const float* W1  = (const float*)d_in[7];
    const float* b1  = (const float*)d_in[8];
    const float* W2  = (const float*)d_in[9];
    const float* b2  = (const float*)d_in[10];
    (void)in_sizes; (void)n_in; (void)out_size; (void)ws_size;

    const int M = 8192, H = 1024, Hh = 512;

    char* ws = (char*)d_ws;
    size_t off = 0;
    auto alloc = [&](size_t bytes) {
        char* p = ws + off;
        off += (bytes + 255) & ~(size_t)255;
        return p;
    };
    u16* Xb     = (u16*)alloc((size_t)M * H * 2);      // residual for Wo
    u16* Wqkvb  = (u16*)alloc((size_t)3 * H * H * 2);
    u16* Wob    = (u16*)alloc((size_t)H * H * 2);
    u16* W1b    = (u16*)alloc((size_t)Hh * H * 2);
    u16* W2b    = (u16*)alloc((size_t)H * Hh * 2);
    u16* Qb     = (u16*)alloc((size_t)M * H * 2);      // reused as hlnb
    u16* Kb     = (u16*)alloc((size_t)M * H * 2);      // reused as Gb
    u16* Vt     = (u16*)alloc((size_t)M * H * 2);
    u16* draftb = (u16*)alloc((size_t)M * H * 2);
    u16* Attb   = (u16*)alloc((size_t)M * H * 2);
    u16* hlnb = Qb;
    u16* Gb   = Kb;
    float* outp = (float*)d_out;

    CastArgs ca;
    ca.src[0] = x;  ca.dst[0] = Xb;                        ca.nblk[0] = (M * H / 8) / 256;
    ca.src[1] = Wq; ca.dst[1] = Wqkvb;                     ca.nblk[1] = (H * H / 8) / 256;
    ca.src[2] = Wk; ca.dst[2] = Wqkvb + (size_t)H * H;     ca.nblk[2] = (H * H / 8) / 256;
    ca.src[3] = Wv; ca.dst[3] = Wqkvb + (size_t)2 * H * H; ca.nblk[3] = (H * H / 8) / 256;
    ca.src[4] = Wo; ca.dst[4] = Wob;                       ca.nblk[4] = (H * H / 8) / 256;
    ca.src[5] = W1; ca.dst[5] = W1b;                       ca.nblk[5] = (Hh * H / 8) / 256;
    ca.src[6] = W2; ca.dst[6] = W2b;                       ca.nblk[6] = (H * Hh / 8) / 256;
    int totblk = 0;
    for (int i = 0; i < 7; ++i) totblk += ca.nblk[i];
    cast_all<<<dim3(totblk), dim3(256), 0, stream>>>(ca);

    // QKV: 256^2 fine-phase, grid 384 (12 col x 32 row), XCD-chunked swizzle
    gemm_qkv2<<<dim3(384), dim3(512), 0, stream>>>(Xb, Wqkvb, Qb, Kb, Vt, H);

    attn_kernel<<<dim3(256), dim3(256), 0, stream>>>(Qb, Kb, Vt, Attb);

    // Wo: ring, grid 256, ncol=8; draftb = bf16(Xb + C)
    gemm_ring<1, 128><<<dim3(256), dim3(512), 0, stream>>>(
        Attb, Wob, nullptr, nullptr, Xb, draftb, nullptr, M, H, H, 8);

    ln_kernel<<<dim3(M), dim3(256), 0, stream>>>(draftb, lnw, lnb, hlnb);

    // W1: ring BN=64, grid 256, ncol=8; Gb = gelu(C + b1)
    gemm_ring<2, 64><<<dim3(256), dim3(512), 0, stream>>>(
        hlnb, W1b, Gb, b1, nullptr, nullptr, nullptr, M, Hh, H, 8);

    // W2: ring, grid 256, ncol=8, K=512; out = draftb + C + b2
    gemm_ring<3, 128><<<dim3(256), dim3(512), 0, stream>>>(
        Gb, W2b, nullptr, b2, nullptr, draftb, outp, M, H, Hh, 8);
}